// Round 7
// baseline (187.618 us; speedup 1.0000x reference)
//
#include <hip/hip_runtime.h>
#include <hip/hip_bf16.h>

#define D 64            // D_IN == D_OUT == 64
#define K 24            // slots/node; deg~Poisson(10): P(>24)~3e-5 -> ~10 spill edges (inline, exact)
#define M44 ((1ULL << 44) - 1)
#define SPILLCAP 65536

typedef __attribute__((ext_vector_type(4))) _Float16 half4;
typedef __attribute__((ext_vector_type(8))) _Float16 half8;
typedef __attribute__((ext_vector_type(4))) float f32x4;   // nt-builtin-compatible

// ---------------------------------------------------------------------------
// k_build v6: XCD-affine row-parity build (r1-PROVEN) + leading prep blocks
// (r5) + NONTEMPORAL STREAMS (r6).
// r6 post-mortem: build WRITE still 62MB = xh 13 + ~48MB slot-line
// writebacks. Affinity pinned each node's slot lines to one L2, but the
// ~11MB/XCD of streaming edge reads evict the ~1.2MB/XCD dirty slot
// working set over and over -> each line written back ~5x half-full.
// Fix: nt-mark all pure streams (rowi/coli/ew reads, prep x reads, xh
// writes) — zero intra-XCD reuse (parity siblings of a chunk land on
// DIFFERENT XCDs, so each XCD reads each line exactly once). Build is
// atomic-bound at 8 VGPR / 77% occ -> nt latency fully hidden (r4's nt
// regression was a dep-chain-head load in a latency-bound kernel; n/a here).
// Slot lines stay resident until kernel end -> ~1 writeback each.
// MEASURED WALLS: ~21.5G RMW/s device atomics -> 46.5us floor for 1M edges;
// 1 edge/thread (r10); separate dispatches (r12).
__global__ __launch_bounds__(256) void k_build(const int* __restrict__ rowi,
                                               const int* __restrict__ coli,
                                               const float* __restrict__ ew,
                                               unsigned long long* __restrict__ packed,
                                               unsigned int* __restrict__ slots,
                                               int4* __restrict__ spill,
                                               int* __restrict__ spillCnt, int nE,
                                               int prepBlocks,
                                               const f32x4* __restrict__ x4,
                                               half8* __restrict__ xh8, int nv) {
    int b = blockIdx.x;
    if (b < prepBlocks) {
        // leading blocks: x fp32 -> fp16 (halves gather traffic; 2^-11 rel
        // err -> ~2e-4 on out, invisible at tolerance). nt both directions:
        // x read once, xh not read in THIS kernel.
        int t = b * 256 + threadIdx.x;
        if (t >= nv) return;
        f32x4 a = __builtin_nontemporal_load(&x4[2 * t]);
        f32x4 bb = __builtin_nontemporal_load(&x4[2 * t + 1]);
        half8 h;
        h[0] = (_Float16)a[0]; h[1] = (_Float16)a[1]; h[2] = (_Float16)a[2]; h[3] = (_Float16)a[3];
        h[4] = (_Float16)bb[0]; h[5] = (_Float16)bb[1]; h[6] = (_Float16)bb[2]; h[7] = (_Float16)bb[3];
        __builtin_nontemporal_store(h, &xh8[t]);
        return;
    }
    int bp = b - prepBlocks;
    int p = bp & 7;                     // parity class this block serves
    int e = (bp >> 3) * 256 + threadIdx.x;
    if (e >= nE) return;
    int r = __builtin_nontemporal_load(&rowi[e]);
    if ((r & 7) != p) return;           // owned by the sibling on the right XCD
    int c = __builtin_nontemporal_load(&coli[e]);
    float w = __builtin_nontemporal_load(&ew[e]);
    unsigned long long fx = (unsigned long long)((double)w * 4294967296.0);
    unsigned long long old = atomicAdd(&packed[r], (1ULL << 44) | fx);
    int rank = (int)(old >> 44);
    if (rank < K) {
        int q = (int)(w * 32768.0f + 0.5f);
        if (q > 32767) q = 32767;
        slots[r * K + rank] = ((unsigned int)c << 15) | (unsigned int)q;   // cached: lines merge in L2
    } else {
        int pI = atomicAdd(spillCnt, 1);
        if (pI < SPILLCAP) spill[pI] = make_int4(r, c, __float_as_int(w), 0);
    }
}

// lazy dis: rsqrt(1 + sum_ew) straight from the packed word.
__device__ __forceinline__ float dis_of(unsigned long long pk) {
    return rsqrtf(1.0f + (float)(pk & M44) * (1.0f / 4294967296.0f));
}

// k_gather_gemm v6 = r5-PROVEN structure (Bs in LDS w/ 2-way-bank staging
// swizzle, cached slot/x loads, BRANCH-FREE inner t-loop — r5 measured:
// gather left top-5, <57us; r4 proved nt LOADS here regress) + nt OUT store
// (25MB written once, never read — frees L2 for xh; tail store, not r4's
// dep-chain-head failure mode).
template <bool H>
__global__ __launch_bounds__(256) void k_gather_gemm(const float* __restrict__ x,
                                                     const _Float16* __restrict__ xh,
                                                     const unsigned long long* __restrict__ packed,
                                                     const unsigned int* __restrict__ slots,
                                                     const int4* __restrict__ spill,
                                                     const int* __restrict__ spillCnt,
                                                     const float* __restrict__ W,
                                                     const float* __restrict__ bias,
                                                     float* __restrict__ out, int n) {
    __shared__ float Bs[D * D];        // 16 KB: Bs[k][o] = W[o][k], swizzled s(k)=k>>2
    __shared__ float Ast[16 * D];      // 4 KB: 16-row A tile, swizzled slots
    float4* Ast4 = (float4*)Ast;
    int tid = threadIdx.x;

    // Phase 0: stage W (issue first; overlaps the gather's global loads).
    // Chunk-swizzle by kc -> exactly 2 lanes/bank on ds_write (free, m136).
    const float4* W4 = (const float4*)W;
#pragma unroll
    for (int v = 0; v < 4; ++v) {
        int idx = tid + v * 256;       // 0..1023
        int o  = idx >> 4;             // out-ch 0..63
        int kc = idx & 15;
        float4 wv = W4[idx];
        int gq = o >> 2, oo = o & 3;
        int cpos = 4 * ((gq + kc) & 15) + oo;
        Bs[(4 * kc + 0) * 64 + cpos] = wv.x;
        Bs[(4 * kc + 1) * 64 + cpos] = wv.y;
        Bs[(4 * kc + 2) * 64 + cpos] = wv.z;
        Bs[(4 * kc + 3) * 64 + cpos] = wv.w;
    }

    // Phase 1: gather (one node per 16-lane group)
    int j   = tid & 15;                // k-chunk lane
    int grp = tid >> 4;                // 0..15
    int i0  = blockIdx.x * 16;
    int i   = i0 + grp;

    float4 acc = make_float4(0.f, 0.f, 0.f, 0.f);
    const float4* x4 = (const float4*)x;
    const half4*  xh4 = (const half4*)xh;
    if (i < n) {
        unsigned long long pk = packed[i];
        // hoisted self-row load: in flight during the whole slot loop
        half4 hi; float4 xi;
        if constexpr (H) hi = xh4[i * 16 + j]; else xi = x4[i * 16 + j];
        int rawc = (int)(pk >> 44);
        int c_n = rawc < K ? rawc : K;
        int s = i * K;
        for (int off = 0; off < c_n; off += 16) {
            int idx = off + j;
            unsigned int rec = 0u;
            float wj = 0.f;
            if (idx < c_n) {           // invalid lanes: rec=0, wj=0 (must NOT
                rec = slots[s + idx];  // read stale slots beyond c_n)
                wj = (float)(rec & 32767u) * (1.0f / 32768.0f) * dis_of(packed[rec >> 15]);
            }
            // BRANCH-FREE: all 16 iterations run; invalid t has w=0 (adds 0)
            // and col=0 (x row 0, L1-resident broadcast). Loads issue
            // back-to-back -> full MLP.
#pragma unroll
            for (int t = 0; t < 16; ++t) {
                int col = (int)((unsigned int)__shfl((int)rec, t, 16) >> 15);
                float w = __shfl(wj, t, 16);
                if constexpr (H) {
                    half4 hv = xh4[col * 16 + j];
                    acc.x += w * (float)hv[0]; acc.y += w * (float)hv[1];
                    acc.z += w * (float)hv[2]; acc.w += w * (float)hv[3];
                } else {
                    float4 xv = x4[col * 16 + j];
                    acc.x += w * xv.x; acc.y += w * xv.y;
                    acc.z += w * xv.z; acc.w += w * xv.w;
                }
            }
        }
        if (rawc > K) {                // statistically ~10 edges in the graph
            int total = *spillCnt;
            if (total > SPILLCAP) total = SPILLCAP;
            for (int sp = 0; sp < total; ++sp) {
                int4 v = spill[sp];    // broadcast (same addr all lanes)
                if (v.x == i) {
                    float w = __int_as_float(v.z) * dis_of(packed[v.y]);
                    if constexpr (H) {
                        half4 hv = xh4[v.y * 16 + j];
                        acc.x += w * (float)hv[0]; acc.y += w * (float)hv[1];
                        acc.z += w * (float)hv[2]; acc.w += w * (float)hv[3];
                    } else {
                        float4 xv = x4[v.y * 16 + j];
                        acc.x += w * xv.x; acc.y += w * xv.y;
                        acc.z += w * xv.z; acc.w += w * xv.w;
                    }
                }
            }
        }
        float di = dis_of(pk);
        if constexpr (H) {
            acc.x = di * (di * (float)hi[0] + acc.x);
            acc.y = di * (di * (float)hi[1] + acc.y);
            acc.z = di * (di * (float)hi[2] + acc.z);
            acc.w = di * (di * (float)hi[3] + acc.w);
        } else {
            acc.x = di * (di * xi.x + acc.x);
            acc.y = di * (di * xi.y + acc.y);
            acc.z = di * (di * xi.z + acc.z);
            acc.w = di * (di * xi.w + acc.w);
        }
    }
    Ast4[grp * 16 + ((j + (grp >> 2)) & 15)] = acc;   // swizzled slot
    __syncthreads();                   // covers Bs staging + Ast tile

    // Phase 2: 16x64 mini-GEMM (thread: row=grp', out-chs 4j..4j+3)
    int row = tid >> 4;
    int cg  = tid & 15;
    float4 oacc = ((const float4*)bias)[cg];
#pragma unroll 4
    for (int kc = 0; kc < 16; ++kc) {
        float4 a4 = Ast4[row * 16 + ((kc + (row >> 2)) & 15)];
        int cp = 4 * ((cg + kc) & 15);             // read swizzle matches staging
        float4 b0 = *(const float4*)&Bs[(4 * kc + 0) * 64 + cp];
        float4 b1 = *(const float4*)&Bs[(4 * kc + 1) * 64 + cp];
        float4 b2 = *(const float4*)&Bs[(4 * kc + 2) * 64 + cp];
        float4 b3 = *(const float4*)&Bs[(4 * kc + 3) * 64 + cp];
        oacc.x += a4.x * b0.x + a4.y * b1.x + a4.z * b2.x + a4.w * b3.x;
        oacc.y += a4.x * b0.y + a4.y * b1.y + a4.z * b2.y + a4.w * b3.y;
        oacc.z += a4.x * b0.z + a4.y * b1.z + a4.z * b2.z + a4.w * b3.z;
        oacc.w += a4.x * b0.w + a4.y * b1.w + a4.z * b2.w + a4.w * b3.w;
    }
    int r = i0 + row;
    if (r < n) {
        f32x4 o4 = { oacc.x, oacc.y, oacc.z, oacc.w };
        __builtin_nontemporal_store(o4, &((f32x4*)out)[r * 16 + cg]);
    }
}

extern "C" void kernel_launch(void* const* d_in, const int* in_sizes, int n_in,
                              void* d_out, int out_size, void* d_ws, size_t ws_size,
                              hipStream_t stream) {
    const float* x    = (const float*)d_in[0];
    const int*   ei   = (const int*)d_in[1];   // [2*E] flat: rows then cols
    const float* ew   = (const float*)d_in[2];
    const float* W    = (const float*)d_in[3];
    const float* bias = (const float*)d_in[4];
    float* out = (float*)d_out;

    int n  = in_sizes[0] / D;   // 100000
    int nE = in_sizes[2];       // 1000000
    const int* rowi = ei;
    const int* coli = ei + nE;

    // workspace: packed | spillCnt | slots | spill | xh(fp16)
    char* w = (char*)d_ws;
    unsigned long long* packed = (unsigned long long*)w; w += (size_t)n * 8;
    int* spillCnt = (int*)w;                             w += 64;
    unsigned int* slots = (unsigned int*)w;              w += (size_t)n * K * 4;
    int4* spill = (int4*)w;                              w += (size_t)SPILLCAP * 16;
    _Float16* xh = (_Float16*)w;

    size_t need = (size_t)n * 8 + 64 + (size_t)n * K * 4 + (size_t)SPILLCAP * 16
                + (size_t)n * D * 2;
    int useH = ws_size >= need ? 1 : 0;

    int gE = (nE + 255) / 256;
    int buildBlocks = gE * 8;
    int nv = n * D / 8;         // 800000 half8s
    int prepBlocks = useH ? (nv + 255) / 256 : 0;   // leading blocks
    int gT = (n + 15) / 16;     // 6250 blocks: 16 nodes/block, 1 node/group

    hipMemsetAsync(packed, 0, (size_t)n * 8 + 64, stream);   // packed + spillCnt
    k_build<<<prepBlocks + buildBlocks, 256, 0, stream>>>(
        rowi, coli, ew, packed, slots, spill, spillCnt, nE,
        prepBlocks, (const f32x4*)x, (half8*)xh, nv);
    if (useH)
        k_gather_gemm<true><<<gT, 256, 0, stream>>>(x, xh, packed, slots, spill, spillCnt, W, bias, out, n);
    else
        k_gather_gemm<false><<<gT, 256, 0, stream>>>(x, xh, packed, slots, spill, spillCnt, W, bias, out, n);
}

// Round 8
// 178.608 us; speedup vs baseline: 1.0504x; 1.0504x over previous
//
#include <hip/hip_runtime.h>
#include <hip/hip_bf16.h>

#define D 64            // D_IN == D_OUT == 64
#define K 24            // slots/node; deg~Poisson(10): P(>24)~3e-5 -> ~10 spill edges (inline, exact)
#define M44 ((1ULL << 44) - 1)
#define SPILLCAP 65536

typedef __attribute__((ext_vector_type(4))) _Float16 half4;
typedef __attribute__((ext_vector_type(8))) _Float16 half8;

// ---------------------------------------------------------------------------
// k_build v5 (r6-PROVEN, r7's nt REVERTED: nt did NOT cut WRITE_SIZE and
// total regressed — nt is off the table; the ~60MB slot writeback is
// structural). XCD-affine row-parity build + leading prep blocks.
// prepBlocks PADDED to a multiple of 8 so build block bp's XCD == parity
// class bp&7 == the node parity it writes (needed by the gather remap).
// MEASURED WALLS: ~21.5G RMW/s device atomics -> 46.5us floor for 1M edges;
// 1 edge/thread (r10); separate dispatches (r12).
__global__ __launch_bounds__(256) void k_build(const int* __restrict__ rowi,
                                               const int* __restrict__ coli,
                                               const float* __restrict__ ew,
                                               unsigned long long* __restrict__ packed,
                                               unsigned int* __restrict__ slots,
                                               int4* __restrict__ spill,
                                               int* __restrict__ spillCnt, int nE,
                                               int prepBlocks,
                                               const float4* __restrict__ x4,
                                               half8* __restrict__ xh8, int nv) {
    int b = blockIdx.x;
    if (b < prepBlocks) {
        // leading blocks (r5-proven: front placement overlaps the atomic
        // wall): x fp32 -> fp16, UNSCALED (dis not known yet; k_scale folds
        // it in after build).
        int t = b * 256 + threadIdx.x;
        if (t >= nv) return;
        float4 a = x4[2 * t], bb = x4[2 * t + 1];
        half8 h;
        h[0] = (_Float16)a.x; h[1] = (_Float16)a.y; h[2] = (_Float16)a.z; h[3] = (_Float16)a.w;
        h[4] = (_Float16)bb.x; h[5] = (_Float16)bb.y; h[6] = (_Float16)bb.z; h[7] = (_Float16)bb.w;
        xh8[t] = h;
        return;
    }
    int bp = b - prepBlocks;            // prepBlocks % 8 == 0 -> XCD(b) == bp&7
    int p = bp & 7;                     // parity class this block serves
    int e = (bp >> 3) * 256 + threadIdx.x;
    if (e >= nE) return;
    int r = rowi[e];
    if ((r & 7) != p) return;           // owned by the sibling on the right XCD
    int c = coli[e];
    float w = ew[e];
    unsigned long long fx = (unsigned long long)((double)w * 4294967296.0);
    unsigned long long old = atomicAdd(&packed[r], (1ULL << 44) | fx);
    int rank = (int)(old >> 44);
    if (rank < K) {
        int q = (int)(w * 32768.0f + 0.5f);
        if (q > 32767) q = 32767;
        slots[r * K + rank] = ((unsigned int)c << 15) | (unsigned int)q;
    } else {
        int pI = atomicAdd(spillCnt, 1);
        if (pI < SPILLCAP) spill[pI] = make_int4(r, c, __float_as_int(w), 0);
    }
}

// lazy dis: rsqrt(1 + sum_ew) straight from the packed word. packed sums
// include ALL edges (spilled too) -> exact for every node.
__device__ __forceinline__ float dis_of(unsigned long long pk) {
    return rsqrtf(1.0f + (float)(pk & M44) * (1.0f / 4294967296.0f));
}

// k_scale (r8): xh[i] *= dis_i, in place. After this, gather's per-edge
// work needs NO packed[col] load and NO rsqrt: message = q15 * xh'[col],
// self term = xh'[i], final row scale = dis_i. Removes the dependent
// random 8B load + rsqrt from the gather's critical chain (1M times).
// 26MB streaming, ~5-7us.
__global__ __launch_bounds__(256) void k_scale(const unsigned long long* __restrict__ packed,
                                               half8* __restrict__ xh8, int nv8) {
    int t = blockIdx.x * 256 + threadIdx.x;
    if (t >= nv8) return;
    float dis = dis_of(packed[t >> 3]);   // 8 threads/row share one 8B word
    half8 h = xh8[t];
#pragma unroll
    for (int k = 0; k < 8; ++k) h[k] = (_Float16)((float)h[k] * dis);
    xh8[t] = h;
}

// k_gather_gemm v7 = r5-PROVEN core (Bs in LDS w/ 2-way-bank staging
// swizzle, BRANCH-FREE inner t-loop, hoisted self-row load) with:
//  (a) dis-folded xh' (H path): per-edge w = q15/32768 computed from the
//      shfl'd record — one shfl instead of two, no packed load, no rsqrt.
//  (b) PARITY-REMAPPED grid: block b (XCD b&7 by round-robin) handles nodes
//      i ≡ b&7 (mod 8) — same parity whose slot lines build dirtied on
//      that XCD -> slot reads become same-L2 hits where lines survive.
template <bool H>
__global__ __launch_bounds__(256) void k_gather_gemm(const float* __restrict__ x,
                                                     const _Float16* __restrict__ xh,
                                                     const unsigned long long* __restrict__ packed,
                                                     const unsigned int* __restrict__ slots,
                                                     const int4* __restrict__ spill,
                                                     const int* __restrict__ spillCnt,
                                                     const float* __restrict__ W,
                                                     const float* __restrict__ bias,
                                                     float* __restrict__ out, int n) {
    __shared__ float Bs[D * D];        // 16 KB: Bs[k][o] = W[o][k], swizzled
    __shared__ float Ast[16 * D];      // 4 KB: 16-row A tile, swizzled slots
    float4* Ast4 = (float4*)Ast;
    int tid = threadIdx.x;

    // Phase 0: stage W (issue first; overlaps the gather's global loads).
    // Chunk-swizzle by kc -> exactly 2 lanes/bank on ds_write (free, m136).
    const float4* W4 = (const float4*)W;
#pragma unroll
    for (int v = 0; v < 4; ++v) {
        int idx = tid + v * 256;       // 0..1023
        int o  = idx >> 4;             // out-ch 0..63
        int kc = idx & 15;
        float4 wv = W4[idx];
        int gq = o >> 2, oo = o & 3;
        int cpos = 4 * ((gq + kc) & 15) + oo;
        Bs[(4 * kc + 0) * 64 + cpos] = wv.x;
        Bs[(4 * kc + 1) * 64 + cpos] = wv.y;
        Bs[(4 * kc + 2) * 64 + cpos] = wv.z;
        Bs[(4 * kc + 3) * 64 + cpos] = wv.w;
    }

    // Phase 1: gather (one node per 16-lane group), parity-remapped
    int j   = tid & 15;                // k-chunk lane
    int grp = tid >> 4;                // 0..15
    int cls = blockIdx.x & 7;          // parity class == XCD (round-robin)
    int q   = blockIdx.x >> 3;
    int i   = ((q * 16 + grp) << 3) + cls;   // node ≡ cls (mod 8)

    float4 acc = make_float4(0.f, 0.f, 0.f, 0.f);
    const float4* x4 = (const float4*)x;
    const half4*  xh4 = (const half4*)xh;
    if (i < n) {
        unsigned long long pk = packed[i];
        // hoisted self-row load: in flight during the whole slot loop
        half4 hi; float4 xi;
        if constexpr (H) hi = xh4[i * 16 + j]; else xi = x4[i * 16 + j];
        int rawc = (int)(pk >> 44);
        int c_n = rawc < K ? rawc : K;
        int s = i * K;
        for (int off = 0; off < c_n; off += 16) {
            int idx = off + j;
            unsigned int rec = 0u;
            float wj = 0.f;
            if (idx < c_n) {           // invalid lanes: rec=0 (w=0, col=0)
                rec = slots[s + idx];
                if constexpr (!H)
                    wj = (float)(rec & 32767u) * (1.0f / 32768.0f) * dis_of(packed[rec >> 15]);
            }
            // BRANCH-FREE (r5-proven): all 16 iterations run; invalid t has
            // w=0 (adds 0) and col=0 (L1-resident row). Loads issue
            // back-to-back -> full MLP.
#pragma unroll
            for (int t = 0; t < 16; ++t) {
                unsigned int rt = (unsigned int)__shfl((int)rec, t, 16);
                int col = (int)(rt >> 15);
                if constexpr (H) {
                    float w = (float)(rt & 32767u) * (1.0f / 32768.0f);
                    half4 hv = xh4[col * 16 + j];   // dis_col folded in
                    acc.x += w * (float)hv[0]; acc.y += w * (float)hv[1];
                    acc.z += w * (float)hv[2]; acc.w += w * (float)hv[3];
                } else {
                    float w = __shfl(wj, t, 16);
                    float4 xv = x4[col * 16 + j];
                    acc.x += w * xv.x; acc.y += w * xv.y;
                    acc.z += w * xv.z; acc.w += w * xv.w;
                }
            }
        }
        if (rawc > K) {                // statistically ~10 edges in the graph
            int total = *spillCnt;
            if (total > SPILLCAP) total = SPILLCAP;
            for (int sp = 0; sp < total; ++sp) {
                int4 v = spill[sp];    // broadcast (same addr all lanes)
                if (v.x == i) {
                    if constexpr (H) {
                        float w = __int_as_float(v.z);   // dis_col in xh'
                        half4 hv = xh4[v.y * 16 + j];
                        acc.x += w * (float)hv[0]; acc.y += w * (float)hv[1];
                        acc.z += w * (float)hv[2]; acc.w += w * (float)hv[3];
                    } else {
                        float w = __int_as_float(v.z) * dis_of(packed[v.y]);
                        float4 xv = x4[v.y * 16 + j];
                        acc.x += w * xv.x; acc.y += w * xv.y;
                        acc.z += w * xv.z; acc.w += w * xv.w;
                    }
                }
            }
        }
        float di = dis_of(pk);
        if constexpr (H) {
            // out_row = di * (sum_msgs + xh'[i])   (xh'[i] = di*x_i)
            acc.x = di * ((float)hi[0] + acc.x);
            acc.y = di * ((float)hi[1] + acc.y);
            acc.z = di * ((float)hi[2] + acc.z);
            acc.w = di * ((float)hi[3] + acc.w);
        } else {
            acc.x = di * (di * xi.x + acc.x);
            acc.y = di * (di * xi.y + acc.y);
            acc.z = di * (di * xi.z + acc.z);
            acc.w = di * (di * xi.w + acc.w);
        }
    }
    Ast4[grp * 16 + ((j + (grp >> 2)) & 15)] = acc;   // swizzled slot
    __syncthreads();                   // covers Bs staging + Ast tile

    // Phase 2: 16x64 mini-GEMM (thread: row=grp', out-chs 4j..4j+3)
    int row = tid >> 4;
    int cg  = tid & 15;
    float4 oacc = ((const float4*)bias)[cg];
#pragma unroll 4
    for (int kc = 0; kc < 16; ++kc) {
        float4 a4 = Ast4[row * 16 + ((kc + (row >> 2)) & 15)];
        int cp = 4 * ((cg + kc) & 15);             // read swizzle matches staging
        float4 b0 = *(const float4*)&Bs[(4 * kc + 0) * 64 + cp];
        float4 b1 = *(const float4*)&Bs[(4 * kc + 1) * 64 + cp];
        float4 b2 = *(const float4*)&Bs[(4 * kc + 2) * 64 + cp];
        float4 b3 = *(const float4*)&Bs[(4 * kc + 3) * 64 + cp];
        oacc.x += a4.x * b0.x + a4.y * b1.x + a4.z * b2.x + a4.w * b3.x;
        oacc.y += a4.x * b0.y + a4.y * b1.y + a4.z * b2.y + a4.w * b3.y;
        oacc.z += a4.x * b0.z + a4.y * b1.z + a4.z * b2.z + a4.w * b3.z;
        oacc.w += a4.x * b0.w + a4.y * b1.w + a4.z * b2.w + a4.w * b3.w;
    }
    int r = ((q * 16 + row) << 3) + cls;
    if (r < n) ((float4*)out)[r * 16 + cg] = oacc;
}

extern "C" void kernel_launch(void* const* d_in, const int* in_sizes, int n_in,
                              void* d_out, int out_size, void* d_ws, size_t ws_size,
                              hipStream_t stream) {
    const float* x    = (const float*)d_in[0];
    const int*   ei   = (const int*)d_in[1];   // [2*E] flat: rows then cols
    const float* ew   = (const float*)d_in[2];
    const float* W    = (const float*)d_in[3];
    const float* bias = (const float*)d_in[4];
    float* out = (float*)d_out;

    int n  = in_sizes[0] / D;   // 100000
    int nE = in_sizes[2];       // 1000000
    const int* rowi = ei;
    const int* coli = ei + nE;

    // workspace: packed | spillCnt | slots | spill | xh(fp16)
    char* w = (char*)d_ws;
    unsigned long long* packed = (unsigned long long*)w; w += (size_t)n * 8;
    int* spillCnt = (int*)w;                             w += 64;
    unsigned int* slots = (unsigned int*)w;              w += (size_t)n * K * 4;
    int4* spill = (int4*)w;                              w += (size_t)SPILLCAP * 16;
    _Float16* xh = (_Float16*)w;

    size_t need = (size_t)n * 8 + 64 + (size_t)n * K * 4 + (size_t)SPILLCAP * 16
                + (size_t)n * D * 2;
    int useH = ws_size >= need ? 1 : 0;

    int gE = (nE + 255) / 256;
    int buildBlocks = gE * 8;
    int nv = n * D / 8;         // 800000 half8s
    int prepBlocks = useH ? ((((nv + 255) / 256) + 7) & ~7) : 0;  // %8==0 pad
    int nPerClass = (n + 7) / 8;
    int gT = 8 * ((nPerClass + 15) / 16);   // parity-remapped grid (6256)

    hipMemsetAsync(packed, 0, (size_t)n * 8 + 64, stream);   // packed + spillCnt
    k_build<<<prepBlocks + buildBlocks, 256, 0, stream>>>(
        rowi, coli, ew, packed, slots, spill, spillCnt, nE,
        prepBlocks, (const float4*)x, (half8*)xh, nv);
    if (useH) {
        int nv8 = n * 8;
        k_scale<<<(nv8 + 255) / 256, 256, 0, stream>>>(packed, (half8*)xh, nv8);
        k_gather_gemm<true><<<gT, 256, 0, stream>>>(x, xh, packed, slots, spill, spillCnt, W, bias, out, n);
    } else {
        k_gather_gemm<false><<<gT, 256, 0, stream>>>(x, xh, packed, slots, spill, spillCnt, W, bias, out, n);
    }
}

// Round 9
// 177.552 us; speedup vs baseline: 1.0567x; 1.0059x over previous
//
#include <hip/hip_runtime.h>
#include <hip/hip_bf16.h>

#define D 64            // D_IN == D_OUT == 64
#define M44 ((1ULL << 44) - 1)
#define SPILLCAP 65536

typedef __attribute__((ext_vector_type(4))) _Float16 half4;
typedef __attribute__((ext_vector_type(8))) _Float16 half8;

// ---------------------------------------------------------------------------
// k_build v7: XCD-affine row-parity build (r1-PROVEN) + leading prep blocks
// (r5) + LINE-EXCLUSIVE SLOT STRIDE (r9).
// r9 theory: with K=24 a slot row is 96B; 1/3 of 64B lines straddle rows
// r (parity p, XCD p) and r+1 (parity p+1, DIFFERENT XCD) -> shared dirty
// lines ping-pong between non-coherent L2s via partial writebacks = the
// ~48MB excess WRITE that survived affinity (r0) and nt (r7). KS=32 pads
// rows to 128B: every line owned by exactly one row -> one XCD.
// MEASURED WALLS: ~21.5G RMW/s device atomics -> 46.5us floor for 1M edges;
// 1 edge/thread (r10); separate dispatches (r12); nt hints useless (r7).
template <int KS>
__global__ __launch_bounds__(256) void k_build(const int* __restrict__ rowi,
                                               const int* __restrict__ coli,
                                               const float* __restrict__ ew,
                                               unsigned long long* __restrict__ packed,
                                               unsigned int* __restrict__ slots,
                                               int4* __restrict__ spill,
                                               int* __restrict__ spillCnt, int nE,
                                               int prepBlocks,
                                               const float4* __restrict__ x4,
                                               half8* __restrict__ xh8, int nv) {
    int b = blockIdx.x;
    if (b < prepBlocks) {
        // leading blocks (r5-proven): x fp32 -> fp16, UNSCALED (dis not
        // known yet; k_scale folds it in after build).
        int t = b * 256 + threadIdx.x;
        if (t >= nv) return;
        float4 a = x4[2 * t], bb = x4[2 * t + 1];
        half8 h;
        h[0] = (_Float16)a.x; h[1] = (_Float16)a.y; h[2] = (_Float16)a.z; h[3] = (_Float16)a.w;
        h[4] = (_Float16)bb.x; h[5] = (_Float16)bb.y; h[6] = (_Float16)bb.z; h[7] = (_Float16)bb.w;
        xh8[t] = h;
        return;
    }
    int bp = b - prepBlocks;            // prepBlocks % 8 == 0 -> XCD(b) == bp&7
    int p = bp & 7;                     // parity class this block serves
    int e = (bp >> 3) * 256 + threadIdx.x;
    if (e >= nE) return;
    int r = rowi[e];
    if ((r & 7) != p) return;           // owned by the sibling on the right XCD
    int c = coli[e];
    float w = ew[e];
    unsigned long long fx = (unsigned long long)((double)w * 4294967296.0);
    unsigned long long old = atomicAdd(&packed[r], (1ULL << 44) | fx);
    int rank = (int)(old >> 44);
    if (rank < KS) {
        int q = (int)(w * 32768.0f + 0.5f);
        if (q > 32767) q = 32767;
        slots[r * KS + rank] = ((unsigned int)c << 15) | (unsigned int)q;
    } else {                            // KS=32: P(deg>32)~1e-9, list empty
        int pI = atomicAdd(spillCnt, 1);
        if (pI < SPILLCAP) spill[pI] = make_int4(r, c, __float_as_int(w), 0);
    }
}

// lazy dis: rsqrt(1 + sum_ew) straight from the packed word. packed sums
// include ALL edges (spilled too) -> exact for every node.
__device__ __forceinline__ float dis_of(unsigned long long pk) {
    return rsqrtf(1.0f + (float)(pk & M44) * (1.0f / 4294967296.0f));
}

// k_scale (r8): xh[i] *= dis_i in place. Gather's per-edge work then needs
// NO packed[col] load and NO rsqrt. ~26MB L3-resident streaming, ~5us.
__global__ __launch_bounds__(256) void k_scale(const unsigned long long* __restrict__ packed,
                                               half8* __restrict__ xh8, int nv8) {
    int t = blockIdx.x * 256 + threadIdx.x;
    if (t >= nv8) return;
    float dis = dis_of(packed[t >> 3]);   // 8 threads/row share one 8B word
    half8 h = xh8[t];
#pragma unroll
    for (int k = 0; k < 8; ++k) h[k] = (_Float16)((float)h[k] * dis);
    xh8[t] = h;
}

// k_gather_gemm v8 = r8 structure (r5-PROVEN core: Bs in LDS w/ 2-way-bank
// staging swizzle, BRANCH-FREE inner t-loop, hoisted self-row load;
// r8: dis-folded xh', parity-remapped grid -> slot reads hit the same-XCD
// L2 the build dirtied) with KS-templated slot stride (KS=32 line-exclusive).
template <int KS, bool H>
__global__ __launch_bounds__(256) void k_gather_gemm(const float* __restrict__ x,
                                                     const _Float16* __restrict__ xh,
                                                     const unsigned long long* __restrict__ packed,
                                                     const unsigned int* __restrict__ slots,
                                                     const int4* __restrict__ spill,
                                                     const int* __restrict__ spillCnt,
                                                     const float* __restrict__ W,
                                                     const float* __restrict__ bias,
                                                     float* __restrict__ out, int n) {
    __shared__ float Bs[D * D];        // 16 KB: Bs[k][o] = W[o][k], swizzled
    __shared__ float Ast[16 * D];      // 4 KB: 16-row A tile, swizzled slots
    float4* Ast4 = (float4*)Ast;
    int tid = threadIdx.x;

    // Phase 0: stage W (issue first; overlaps the gather's global loads).
    // Chunk-swizzle by kc -> exactly 2 lanes/bank on ds_write (free, m136).
    const float4* W4 = (const float4*)W;
#pragma unroll
    for (int v = 0; v < 4; ++v) {
        int idx = tid + v * 256;       // 0..1023
        int o  = idx >> 4;             // out-ch 0..63
        int kc = idx & 15;
        float4 wv = W4[idx];
        int gq = o >> 2, oo = o & 3;
        int cpos = 4 * ((gq + kc) & 15) + oo;
        Bs[(4 * kc + 0) * 64 + cpos] = wv.x;
        Bs[(4 * kc + 1) * 64 + cpos] = wv.y;
        Bs[(4 * kc + 2) * 64 + cpos] = wv.z;
        Bs[(4 * kc + 3) * 64 + cpos] = wv.w;
    }

    // Phase 1: gather (one node per 16-lane group), parity-remapped:
    // block b -> XCD b&7 (round-robin) handles nodes i ≡ b&7 (mod 8).
    int j   = tid & 15;                // k-chunk lane
    int grp = tid >> 4;                // 0..15
    int cls = blockIdx.x & 7;
    int q   = blockIdx.x >> 3;
    int i   = ((q * 16 + grp) << 3) + cls;

    float4 acc = make_float4(0.f, 0.f, 0.f, 0.f);
    const float4* x4 = (const float4*)x;
    const half4*  xh4 = (const half4*)xh;
    if (i < n) {
        unsigned long long pk = packed[i];
        // hoisted self-row load: in flight during the whole slot loop
        half4 hi; float4 xi;
        if constexpr (H) hi = xh4[i * 16 + j]; else xi = x4[i * 16 + j];
        int rawc = (int)(pk >> 44);
        int c_n = rawc < KS ? rawc : KS;
        int s = i * KS;
        for (int off = 0; off < c_n; off += 16) {
            int idx = off + j;
            unsigned int rec = 0u;
            float wj = 0.f;
            if (idx < c_n) {           // invalid lanes: rec=0 (w=0, col=0)
                rec = slots[s + idx];
                if constexpr (!H)
                    wj = (float)(rec & 32767u) * (1.0f / 32768.0f) * dis_of(packed[rec >> 15]);
            }
            // BRANCH-FREE (r5-proven): all 16 iterations run; invalid t has
            // w=0 (adds 0) and col=0 (L1-resident row). Loads issue
            // back-to-back -> full MLP.
#pragma unroll
            for (int t = 0; t < 16; ++t) {
                unsigned int rt = (unsigned int)__shfl((int)rec, t, 16);
                int col = (int)(rt >> 15);
                if constexpr (H) {
                    float w = (float)(rt & 32767u) * (1.0f / 32768.0f);
                    half4 hv = xh4[col * 16 + j];   // dis_col folded in
                    acc.x += w * (float)hv[0]; acc.y += w * (float)hv[1];
                    acc.z += w * (float)hv[2]; acc.w += w * (float)hv[3];
                } else {
                    float w = __shfl(wj, t, 16);
                    float4 xv = x4[col * 16 + j];
                    acc.x += w * xv.x; acc.y += w * xv.y;
                    acc.z += w * xv.z; acc.w += w * xv.w;
                }
            }
        }
        if (rawc > KS) {               // KS=32: essentially never
            int total = *spillCnt;
            if (total > SPILLCAP) total = SPILLCAP;
            for (int sp = 0; sp < total; ++sp) {
                int4 v = spill[sp];    // broadcast (same addr all lanes)
                if (v.x == i) {
                    if constexpr (H) {
                        float w = __int_as_float(v.z);   // dis_col in xh'
                        half4 hv = xh4[v.y * 16 + j];
                        acc.x += w * (float)hv[0]; acc.y += w * (float)hv[1];
                        acc.z += w * (float)hv[2]; acc.w += w * (float)hv[3];
                    } else {
                        float w = __int_as_float(v.z) * dis_of(packed[v.y]);
                        float4 xv = x4[v.y * 16 + j];
                        acc.x += w * xv.x; acc.y += w * xv.y;
                        acc.z += w * xv.z; acc.w += w * xv.w;
                    }
                }
            }
        }
        float di = dis_of(pk);
        if constexpr (H) {
            // out_row = di * (sum_msgs + xh'[i])   (xh'[i] = di*x_i)
            acc.x = di * ((float)hi[0] + acc.x);
            acc.y = di * ((float)hi[1] + acc.y);
            acc.z = di * ((float)hi[2] + acc.z);
            acc.w = di * ((float)hi[3] + acc.w);
        } else {
            acc.x = di * (di * xi.x + acc.x);
            acc.y = di * (di * xi.y + acc.y);
            acc.z = di * (di * xi.z + acc.z);
            acc.w = di * (di * xi.w + acc.w);
        }
    }
    Ast4[grp * 16 + ((j + (grp >> 2)) & 15)] = acc;   // swizzled slot
    __syncthreads();                   // covers Bs staging + Ast tile

    // Phase 2: 16x64 mini-GEMM (thread: row=grp', out-chs 4j..4j+3)
    int row = tid >> 4;
    int cg  = tid & 15;
    float4 oacc = ((const float4*)bias)[cg];
#pragma unroll 4
    for (int kc = 0; kc < 16; ++kc) {
        float4 a4 = Ast4[row * 16 + ((kc + (row >> 2)) & 15)];
        int cp = 4 * ((cg + kc) & 15);             // read swizzle matches staging
        float4 b0 = *(const float4*)&Bs[(4 * kc + 0) * 64 + cp];
        float4 b1 = *(const float4*)&Bs[(4 * kc + 1) * 64 + cp];
        float4 b2 = *(const float4*)&Bs[(4 * kc + 2) * 64 + cp];
        float4 b3 = *(const float4*)&Bs[(4 * kc + 3) * 64 + cp];
        oacc.x += a4.x * b0.x + a4.y * b1.x + a4.z * b2.x + a4.w * b3.x;
        oacc.y += a4.x * b0.y + a4.y * b1.y + a4.z * b2.y + a4.w * b3.y;
        oacc.z += a4.x * b0.z + a4.y * b1.z + a4.z * b2.z + a4.w * b3.z;
        oacc.w += a4.x * b0.w + a4.y * b1.w + a4.z * b2.w + a4.w * b3.w;
    }
    int r = ((q * 16 + row) << 3) + cls;
    if (r < n) ((float4*)out)[r * 16 + cg] = oacc;
}

extern "C" void kernel_launch(void* const* d_in, const int* in_sizes, int n_in,
                              void* d_out, int out_size, void* d_ws, size_t ws_size,
                              hipStream_t stream) {
    const float* x    = (const float*)d_in[0];
    const int*   ei   = (const int*)d_in[1];   // [2*E] flat: rows then cols
    const float* ew   = (const float*)d_in[2];
    const float* W    = (const float*)d_in[3];
    const float* bias = (const float*)d_in[4];
    float* out = (float*)d_out;

    int n  = in_sizes[0] / D;   // 100000
    int nE = in_sizes[2];       // 1000000
    const int* rowi = ei;
    const int* coli = ei + nE;

    // aligned workspace: packed | pad | spillCnt(128B) | slots(128B-aligned,
    // KS*4 B/row) | spill | xh(fp16)
    char* base = (char*)d_ws;
    size_t off_packed = 0;
    size_t off_spillCnt = ((size_t)n * 8 + 127) & ~(size_t)127;
    size_t off_slots = off_spillCnt + 128;
    auto mkNeed = [&](int KS, int withH) {
        size_t o = off_slots + (size_t)n * KS * 4 + (size_t)SPILLCAP * 16;
        return o + (withH ? (size_t)n * D * 2 : 0);
    };

    int KS, useH;
    if (ws_size >= mkNeed(32, 1))      { KS = 32; useH = 1; }
    else if (ws_size >= mkNeed(24, 1)) { KS = 24; useH = 1; }
    else                               { KS = 24; useH = 0; }

    unsigned long long* packed = (unsigned long long*)(base + off_packed);
    int* spillCnt = (int*)(base + off_spillCnt);
    unsigned int* slots = (unsigned int*)(base + off_slots);
    int4* spill = (int4*)(base + off_slots + (size_t)n * KS * 4);
    _Float16* xh = (_Float16*)(base + off_slots + (size_t)n * KS * 4 + (size_t)SPILLCAP * 16);

    int gE = (nE + 255) / 256;
    int buildBlocks = gE * 8;
    int nv = n * D / 8;         // 800000 half8s
    int prepBlocks = useH ? ((((nv + 255) / 256) + 7) & ~7) : 0;  // %8==0 pad
    int nPerClass = (n + 7) / 8;
    int gT = 8 * ((nPerClass + 15) / 16);   // parity-remapped grid
    int nv8 = n * 8;

    hipMemsetAsync(packed, 0, off_slots, stream);   // packed + pad + spillCnt
    if (KS == 32) {
        k_build<32><<<prepBlocks + buildBlocks, 256, 0, stream>>>(
            rowi, coli, ew, packed, slots, spill, spillCnt, nE,
            prepBlocks, (const float4*)x, (half8*)xh, nv);
        k_scale<<<(nv8 + 255) / 256, 256, 0, stream>>>(packed, (half8*)xh, nv8);
        k_gather_gemm<32, true><<<gT, 256, 0, stream>>>(x, xh, packed, slots, spill, spillCnt, W, bias, out, n);
    } else if (useH) {
        k_build<24><<<prepBlocks + buildBlocks, 256, 0, stream>>>(
            rowi, coli, ew, packed, slots, spill, spillCnt, nE,
            prepBlocks, (const float4*)x, (half8*)xh, nv);
        k_scale<<<(nv8 + 255) / 256, 256, 0, stream>>>(packed, (half8*)xh, nv8);
        k_gather_gemm<24, true><<<gT, 256, 0, stream>>>(x, xh, packed, slots, spill, spillCnt, W, bias, out, n);
    } else {
        k_build<24><<<buildBlocks, 256, 0, stream>>>(
            rowi, coli, ew, packed, slots, spill, spillCnt, nE,
            0, (const float4*)x, (half8*)xh, nv);
        k_gather_gemm<24, false><<<gT, 256, 0, stream>>>(x, xh, packed, slots, spill, spillCnt, W, bias, out, n);
    }
}